// Round 1
// baseline (1230.735 us; speedup 1.0000x reference)
//
#include <hip/hip_runtime.h>
#include <hip/hip_bf16.h>

// Problem constants (SelfAttentionHead: EMB=1024, KEY=HEAD=64, B=4, T=4096)
#define EMB   1024
#define NB    4
#define TT    4096
#define DD    64      // KEY == HEAD == 64

// softmax in base-2 domain: exp(x) == exp2(x * log2(e)); fold in the 1/sqrt(64)=0.125
static constexpr float SCALE2 = 0.125f * 1.4426950408889634f;

// ---------------------------------------------------------------------------
// Kernel 1: fused QKV projection.
//   grid = (NB*TT)/16 = 1024 blocks, block = 192 threads (3 waves).
//   wave 0 -> K = emb@Wk+bk, wave 1 -> Q, wave 2 -> V.
//   Thread owns column d for 16 consecutive rows. emb loads are wave-uniform
//   (scalar path); W loads are lane-coalesced (64 consecutive floats / wave).
// ---------------------------------------------------------------------------
__global__ __launch_bounds__(192) void qkv_proj_kernel(
    const float* __restrict__ emb,
    const float* __restrict__ Wk, const float* __restrict__ bk,
    const float* __restrict__ Wq, const float* __restrict__ bq,
    const float* __restrict__ Wv, const float* __restrict__ bv,
    float* __restrict__ Qb, float* __restrict__ Kb, float* __restrict__ Vb)
{
    const int tid = threadIdx.x;
    const int wv  = tid >> 6;     // 0:K  1:Q  2:V
    const int d   = tid & 63;
    const int m0  = blockIdx.x * 16;

    const float* __restrict__ W    = (wv == 0) ? Wk : (wv == 1) ? Wq : Wv;
    const float* __restrict__ bias = (wv == 0) ? bk : (wv == 1) ? bq : bv;
    float* __restrict__ Op         = (wv == 0) ? Kb : (wv == 1) ? Qb : Vb;

    float acc[16];
#pragma unroll
    for (int r = 0; r < 16; ++r) acc[r] = 0.0f;

    const float* __restrict__ ebase = emb + (size_t)m0 * EMB;

    for (int k = 0; k < EMB; k += 4) {
        const float w0 = W[(k + 0) * DD + d];
        const float w1 = W[(k + 1) * DD + d];
        const float w2 = W[(k + 2) * DD + d];
        const float w3 = W[(k + 3) * DD + d];
#pragma unroll
        for (int r = 0; r < 16; ++r) {
            const float* e = ebase + r * EMB + k;   // wave-uniform address
            acc[r] += e[0] * w0 + e[1] * w1 + e[2] * w2 + e[3] * w3;
        }
    }

    const float bi = bias[d];
#pragma unroll
    for (int r = 0; r < 16; ++r)
        Op[(size_t)(m0 + r) * DD + d] = acc[r] + bi;
}

// ---------------------------------------------------------------------------
// Kernel 2: causal flash attention, fp32.
//   grid = NB * (TT/64) = 256 blocks, block = 512 threads (8 waves).
//   Each block owns a 64-row q-tile. Lane <-> q-row; q[64], o[64] live in
//   VGPRs; online softmax is thread-local. The 8 waves split the key range in
//   interleaved 64-key chunks; K/V row reads are wave-uniform (scalar
//   broadcast). Final merge of the 8 partial states goes through LDS.
// ---------------------------------------------------------------------------
#define NW 8           // waves per block
#define RSTRIDE 65     // padded LDS stride (conflict-free transpose)

__global__ __launch_bounds__(512) void attn_kernel(
    const float* __restrict__ Qb,
    const float* __restrict__ Kb,
    const float* __restrict__ Vb,
    float* __restrict__ out)
{
    __shared__ float red[DD * RSTRIDE];      // [d][row], padded
    __shared__ float mlbuf[NW * 64 * 2];     // (m, l) per wave per row
    __shared__ float ltinv[64];              // 1 / l_total per row

    const int tid  = threadIdx.x;
    const int w    = tid >> 6;
    const int lane = tid & 63;

    const int bt = blockIdx.x;     // 0 .. NB*64-1
    const int b  = bt >> 6;
    const int ti = bt & 63;
    const int m0 = ti * 64;
    const int row = m0 + lane;     // this thread's q row within the batch

    // load q row into registers
    const float* __restrict__ Qrow = Qb + ((size_t)b * TT + row) * DD;
    float q[DD];
#pragma unroll
    for (int d = 0; d < DD; d += 4) {
        float4 v = *reinterpret_cast<const float4*>(Qrow + d);
        q[d] = v.x; q[d + 1] = v.y; q[d + 2] = v.z; q[d + 3] = v.w;
    }

    float m = -1e30f, l = 0.0f;
    float o[DD];
#pragma unroll
    for (int d = 0; d < DD; ++d) o[d] = 0.0f;

    // key chunks: chunk c covers keys [c*64, c*64+64); wave w takes c = w, w+8, ...
    // last chunk intersecting the causal region of this tile is c = ti.
    for (int c = w; c <= ti; c += NW) {
        const int k0 = c * 64;
        const float* __restrict__ Kc = Kb + ((size_t)b * TT + k0) * DD;
        const float* __restrict__ Vc = Vb + ((size_t)b * TT + k0) * DD;

        for (int kk = 0; kk < 64; kk += 8) {
            float s2[8];
#pragma unroll
            for (int j = 0; j < 8; ++j) {
                const float* __restrict__ kr = Kc + (kk + j) * DD;  // wave-uniform
                float a0 = 0.f, a1 = 0.f, a2 = 0.f, a3 = 0.f;
#pragma unroll
                for (int d = 0; d < DD; d += 4) {
                    a0 += q[d + 0] * kr[d + 0];
                    a1 += q[d + 1] * kr[d + 1];
                    a2 += q[d + 2] * kr[d + 2];
                    a3 += q[d + 3] * kr[d + 3];
                }
                const float s = ((a0 + a1) + (a2 + a3)) * SCALE2;
                const int kidx = k0 + kk + j;
                s2[j] = (kidx <= row) ? s : -1e30f;   // causal mask
            }

            float gm = s2[0];
#pragma unroll
            for (int j = 1; j < 8; ++j) gm = fmaxf(gm, s2[j]);
            const float nm = fmaxf(m, gm);
            const float corr = exp2f(m - nm);
            m = nm;
            l *= corr;
#pragma unroll
            for (int d = 0; d < DD; ++d) o[d] *= corr;

#pragma unroll
            for (int j = 0; j < 8; ++j) {
                const float p = exp2f(s2[j] - nm);
                l += p;
                const float* __restrict__ vr = Vc + (kk + j) * DD;  // wave-uniform
#pragma unroll
                for (int d = 0; d < DD; ++d) o[d] += p * vr[d];
            }
        }
    }

    // ---- merge the NW per-wave partial states -----------------------------
    mlbuf[(w * 64 + lane) * 2 + 0] = m;
    mlbuf[(w * 64 + lane) * 2 + 1] = l;
    __syncthreads();

    float M = -1e30f;
#pragma unroll
    for (int ww = 0; ww < NW; ++ww)
        M = fmaxf(M, mlbuf[(ww * 64 + lane) * 2 + 0]);
    float lt = 0.0f;
#pragma unroll
    for (int ww = 0; ww < NW; ++ww)
        lt += mlbuf[(ww * 64 + lane) * 2 + 1] *
              exp2f(mlbuf[(ww * 64 + lane) * 2 + 0] - M);
    const float corr = exp2f(m - M);

    if (w == 0) ltinv[lane] = 1.0f / lt;

    // sequential o reduction into red[d][row] (write stride 1 across lanes ->
    // conflict-free)
    for (int ww = 0; ww < NW; ++ww) {
        if (w == ww) {
            if (ww == 0) {
#pragma unroll
                for (int d = 0; d < DD; ++d) red[d * RSTRIDE + lane] = o[d] * corr;
            } else {
#pragma unroll
                for (int d = 0; d < DD; ++d) red[d * RSTRIDE + lane] += o[d] * corr;
            }
        }
        __syncthreads();
    }

    // cooperative write-out: out[b][m0+r][d] = red[d][r] * ltinv[r]
    const size_t obase = ((size_t)b * TT + m0) * DD;
    for (int idx = tid; idx < 64 * DD; idx += 512) {
        const int r = idx >> 6;
        const int d = idx & 63;
        out[obase + idx] = red[d * RSTRIDE + r] * ltinv[r];
    }
}

// ---------------------------------------------------------------------------
extern "C" void kernel_launch(void* const* d_in, const int* in_sizes, int n_in,
                              void* d_out, int out_size, void* d_ws, size_t ws_size,
                              hipStream_t stream)
{
    const float* emb = (const float*)d_in[0];
    const float* Wk  = (const float*)d_in[1];
    const float* bk  = (const float*)d_in[2];
    const float* Wq  = (const float*)d_in[3];
    const float* bq  = (const float*)d_in[4];
    const float* Wv  = (const float*)d_in[5];
    const float* bv  = (const float*)d_in[6];
    float* out = (float*)d_out;

    // workspace: Q, K, V each (NB*TT) x DD fp32 = 4 MB -> 12 MB total
    float* Qb = (float*)d_ws;
    float* Kb = Qb + (size_t)NB * TT * DD;
    float* Vb = Kb + (size_t)NB * TT * DD;

    qkv_proj_kernel<<<(NB * TT) / 16, 192, 0, stream>>>(
        emb, Wk, bk, Wq, bq, Wv, bv, Qb, Kb, Vb);

    attn_kernel<<<NB * (TT / 64), 512, 0, stream>>>(Qb, Kb, Vb, out);
}

// Round 2
// 228.601 us; speedup vs baseline: 5.3838x; 5.3838x over previous
//
#include <hip/hip_runtime.h>
#include <hip/hip_bf16.h>

// SelfAttentionHead: EMB=1024, KEY=HEAD=64, B=4, T=4096
#define EMB 1024
#define NB  4
#define TT  4096
#define DD  64

// fold 1/sqrt(64) and log2(e) into Q so softmax runs in exp2 domain
static constexpr float SCALE2 = 0.125f * 1.4426950408889634f;

typedef __bf16          bfrag    __attribute__((ext_vector_type(8)));
typedef float           f32x4    __attribute__((ext_vector_type(4)));
typedef unsigned short  ushort8t __attribute__((ext_vector_type(8)));
typedef unsigned short  ushort4t __attribute__((ext_vector_type(4)));

__device__ __forceinline__ unsigned short f2bf(float f) {
    __hip_bfloat16 h = __float2bfloat16(f);   // RNE
    return __builtin_bit_cast(unsigned short, h);
}

// ---------------------------------------------------------------------------
// Prep: Wt[n][k] bf16, n in [0,192) = concat(Wk cols, Wq cols (pre-scaled),
// Wv cols); k contiguous so GEMM staging is a linear coalesced copy.
// ---------------------------------------------------------------------------
__global__ __launch_bounds__(256) void prep_wt(
    const float* __restrict__ Wk, const float* __restrict__ Wq,
    const float* __restrict__ Wv, unsigned short* __restrict__ Wt)
{
    const int o = blockIdx.x * 256 + threadIdx.x;   // 0 .. 192*1024-1
    const int n = o >> 10, k = o & 1023;
    float v;
    if (n < 64)       v = Wk[k * 64 + n];
    else if (n < 128) v = Wq[k * 64 + (n - 64)] * SCALE2;
    else              v = Wv[k * 64 + (n - 128)];
    Wt[o] = f2bf(v);
}

// ---------------------------------------------------------------------------
// QKV projection as bf16 MFMA GEMM. grid=256 (M-tile 64), block=256 (4 waves),
// each wave owns a 16-row strip x all 192 output cols. emb f32 converted to
// bf16 during LDS staging. Outputs: Qb/Kb bf16 [b*t][64] row-major (Q
// pre-scaled), Vt bf16 [b][h][t] (transposed for the attention PV B-operand).
// ---------------------------------------------------------------------------
#define PSTR 72   // padded LDS row stride (bf16 elems): 144B -> 2-way conflicts only

__global__ __launch_bounds__(256) void qkv_mfma(
    const float* __restrict__ emb,
    const unsigned short* __restrict__ Wt,
    const float* __restrict__ bk, const float* __restrict__ bq,
    const float* __restrict__ bv,
    unsigned short* __restrict__ Qb, unsigned short* __restrict__ Kb,
    unsigned short* __restrict__ Vt)
{
    __shared__ unsigned short elds[64 * PSTR];
    __shared__ unsigned short wlds[192 * PSTR];

    const int tid = threadIdx.x;
    const int w = tid >> 6, l = tid & 63;
    const int lr = l & 15, lg = l >> 4;
    const int m0 = blockIdx.x * 64;

    f32x4 acc[12];
#pragma unroll
    for (int i = 0; i < 12; ++i) acc[i] = (f32x4){0.f, 0.f, 0.f, 0.f};

    const int er = tid >> 2, ec = (tid & 3) * 16;   // emb staging: row, col16

    for (int k0 = 0; k0 < EMB; k0 += 64) {
        // stage emb 64x64 f32 -> bf16 (each thread: 16 elems = 4 float4)
        {
            const float* src = emb + (size_t)(m0 + er) * EMB + k0 + ec;
            float4 f0 = *(const float4*)(src + 0);
            float4 f1 = *(const float4*)(src + 4);
            float4 f2 = *(const float4*)(src + 8);
            float4 f3 = *(const float4*)(src + 12);
            ushort8t lo, hi;
            lo[0]=f2bf(f0.x); lo[1]=f2bf(f0.y); lo[2]=f2bf(f0.z); lo[3]=f2bf(f0.w);
            lo[4]=f2bf(f1.x); lo[5]=f2bf(f1.y); lo[6]=f2bf(f1.z); lo[7]=f2bf(f1.w);
            hi[0]=f2bf(f2.x); hi[1]=f2bf(f2.y); hi[2]=f2bf(f2.z); hi[3]=f2bf(f2.w);
            hi[4]=f2bf(f3.x); hi[5]=f2bf(f3.y); hi[6]=f2bf(f3.z); hi[7]=f2bf(f3.w);
            *(ushort8t*)&elds[er * PSTR + ec]     = lo;
            *(ushort8t*)&elds[er * PSTR + ec + 8] = hi;
        }
        // stage Wt 192x64 bf16 (linear coalesced)
#pragma unroll
        for (int i = 0; i < 6; ++i) {
            const int idx = tid + i * 256;
            const int row = idx >> 3, c = (idx & 7) * 8;
            *(ushort8t*)&wlds[row * PSTR + c] =
                *(const ushort8t*)&Wt[(size_t)row * 1024 + k0 + c];
        }
        __syncthreads();
#pragma unroll
        for (int c = 0; c < 2; ++c) {
            bfrag a = *(const bfrag*)&elds[(w * 16 + lr) * PSTR + c * 32 + lg * 8];
#pragma unroll
            for (int nt = 0; nt < 12; ++nt) {
                bfrag bb = *(const bfrag*)&wlds[(nt * 16 + lr) * PSTR + c * 32 + lg * 8];
                acc[nt] = __builtin_amdgcn_mfma_f32_16x16x32_bf16(a, bb, acc[nt], 0, 0, 0);
            }
        }
        __syncthreads();
    }

    // epilogue: C layout col=lane&15, row=(lane>>4)*4+reg
    const int rbase = m0 + w * 16 + lg * 4;
#pragma unroll
    for (int nt = 0; nt < 12; ++nt) {
        const int n = nt * 16 + lr;
        float bias;
        if (n < 64)       bias = bk[n];
        else if (n < 128) bias = bq[n - 64] * SCALE2;
        else              bias = bv[n - 128];
        if (nt < 8) {
            unsigned short* dst = (nt < 4) ? Kb : Qb;
            const int d = (nt < 4) ? n : (n - 64);
#pragma unroll
            for (int rg = 0; rg < 4; ++rg)
                dst[(size_t)(rbase + rg) * 64 + d] = f2bf(acc[nt][rg] + bias);
        } else {
            const int h = n - 128;
            const int b = rbase >> 12, t = rbase & (TT - 1);
            ushort4t pk;
#pragma unroll
            for (int rg = 0; rg < 4; ++rg) pk[rg] = f2bf(acc[nt][rg] + bias);
            *(ushort4t*)&Vt[((size_t)b * 64 + h) * TT + t] = pk;
        }
    }
}

// ---------------------------------------------------------------------------
// Flash attention, bf16 MFMA. grid=512 (heavy-first), block=128 (2 waves).
// q-tile 32 rows (16/wave), k-tile 64 keys. K and V^T staged in padded LDS;
// P goes through LDS bf16 (each wave reads only the rows it wrote -> no
// barrier between write and PV read; DS ops are in-order per wave).
// ---------------------------------------------------------------------------
#define ASTR 72

__global__ __launch_bounds__(128) void attn_mfma(
    const unsigned short* __restrict__ Qb,
    const unsigned short* __restrict__ Kb,
    const unsigned short* __restrict__ Vt,
    float* __restrict__ out)
{
    __shared__ unsigned short klds[64 * ASTR];
    __shared__ unsigned short vlds[64 * ASTR];
    __shared__ unsigned short plds[32 * ASTR];

    const int tid = threadIdx.x;
    const int w = tid >> 6, l = tid & 63;
    const int lr = l & 15, lg = l >> 4;

    const int r  = blockIdx.x;          // 0..511, heavy-first
    const int ti = 127 - (r >> 2);      // q-tile index (32 rows each)
    const int b  = r & 3;
    const int q0 = ti * 32;
    const int woff = w * 16;
    const int nkt = (ti >> 1) + 1;      // number of 64-key tiles

    // Q A-fragments (row = lane&15 within strip, k-contiguous 8 bf16)
    bfrag qa0, qa1;
    {
        const size_t qrow = (size_t)(b * TT + q0 + woff + lr) * 64;
        qa0 = *(const bfrag*)&Qb[qrow + 0  + lg * 8];
        qa1 = *(const bfrag*)&Qb[qrow + 32 + lg * 8];
    }

    f32x4 o[4];
#pragma unroll
    for (int i = 0; i < 4; ++i) o[i] = (f32x4){0.f, 0.f, 0.f, 0.f};
    float mrow[4] = {-1e30f, -1e30f, -1e30f, -1e30f};
    float lrow[4] = {0.f, 0.f, 0.f, 0.f};

    const int srow = tid >> 3, scol = (tid & 7) * 8;   // staging coords

    for (int kt = 0; kt < nkt; ++kt) {
        const int k0 = kt * 64;
        // stage K (row-major) and V^T ([h][j]) tiles, 64x64 bf16 each
#pragma unroll
        for (int i = 0; i < 4; ++i) {
            const int row = srow + i * 16;
            *(ushort8t*)&klds[row * ASTR + scol] =
                *(const ushort8t*)&Kb[(size_t)(b * TT + k0 + row) * 64 + scol];
            *(ushort8t*)&vlds[row * ASTR + scol] =
                *(const ushort8t*)&Vt[((size_t)b * 64 + row) * TT + k0 + scol];
        }
        __syncthreads();

        // S = Q K^T  (16x64 strip per wave)
        f32x4 s[4];
#pragma unroll
        for (int i = 0; i < 4; ++i) s[i] = (f32x4){0.f, 0.f, 0.f, 0.f};
#pragma unroll
        for (int nt = 0; nt < 4; ++nt) {
            bfrag kb0 = *(const bfrag*)&klds[(nt * 16 + lr) * ASTR + 0  + lg * 8];
            bfrag kb1 = *(const bfrag*)&klds[(nt * 16 + lr) * ASTR + 32 + lg * 8];
            s[nt] = __builtin_amdgcn_mfma_f32_16x16x32_bf16(qa0, kb0, s[nt], 0, 0, 0);
            s[nt] = __builtin_amdgcn_mfma_f32_16x16x32_bf16(qa1, kb1, s[nt], 0, 0, 0);
        }

        // causal mask: only the last k-tile straddles the diagonal
        if (kt == nkt - 1) {
#pragma unroll
            for (int nt = 0; nt < 4; ++nt) {
                const int key = k0 + nt * 16 + lr;
#pragma unroll
                for (int rg = 0; rg < 4; ++rg) {
                    const int qr = q0 + woff + lg * 4 + rg;
                    if (key > qr) s[nt][rg] = -1e30f;
                }
            }
        }

        // online softmax (row stats live in the reg dim, reduced over the
        // 16-lane column group via shfl_xor)
        float tm[4];
#pragma unroll
        for (int rg = 0; rg < 4; ++rg)
            tm[rg] = fmaxf(fmaxf(s[0][rg], s[1][rg]), fmaxf(s[2][rg], s[3][rg]));
#pragma unroll
        for (int mk = 1; mk <= 8; mk <<= 1)
#pragma unroll
            for (int rg = 0; rg < 4; ++rg)
                tm[rg] = fmaxf(tm[rg], __shfl_xor(tm[rg], mk));

        float corr[4], rs[4];
#pragma unroll
        for (int rg = 0; rg < 4; ++rg) {
            const float nm = fmaxf(mrow[rg], tm[rg]);
            corr[rg] = exp2f(mrow[rg] - nm);
            mrow[rg] = nm;
            rs[rg] = 0.f;
        }
        float p[4][4];
#pragma unroll
        for (int nt = 0; nt < 4; ++nt)
#pragma unroll
            for (int rg = 0; rg < 4; ++rg) {
                const float pp = exp2f(s[nt][rg] - mrow[rg]);
                p[nt][rg] = pp;
                rs[rg] += pp;
            }
#pragma unroll
        for (int mk = 1; mk <= 8; mk <<= 1)
#pragma unroll
            for (int rg = 0; rg < 4; ++rg)
                rs[rg] += __shfl_xor(rs[rg], mk);
#pragma unroll
        for (int rg = 0; rg < 4; ++rg)
            lrow[rg] = lrow[rg] * corr[rg] + rs[rg];
#pragma unroll
        for (int nt = 0; nt < 4; ++nt)
#pragma unroll
            for (int rg = 0; rg < 4; ++rg)
                o[nt][rg] *= corr[rg];

        // P -> LDS bf16 (this wave's 16 rows)
#pragma unroll
        for (int nt = 0; nt < 4; ++nt)
#pragma unroll
            for (int rg = 0; rg < 4; ++rg)
                plds[(woff + lg * 4 + rg) * ASTR + nt * 16 + lr] = f2bf(p[nt][rg]);

        // PV: O += P V  (A=P from own rows, B=V^T tile)
#pragma unroll
        for (int c = 0; c < 2; ++c) {
            bfrag pa = *(const bfrag*)&plds[(woff + lr) * ASTR + c * 32 + lg * 8];
#pragma unroll
            for (int ht = 0; ht < 4; ++ht) {
                bfrag vb = *(const bfrag*)&vlds[(ht * 16 + lr) * ASTR + c * 32 + lg * 8];
                o[ht] = __builtin_amdgcn_mfma_f32_16x16x32_bf16(pa, vb, o[ht], 0, 0, 0);
            }
        }
        __syncthreads();   // before next tile's staging overwrites K/V
    }

    // epilogue: normalize and store fp32
    float inv[4];
#pragma unroll
    for (int rg = 0; rg < 4; ++rg) inv[rg] = 1.0f / lrow[rg];
#pragma unroll
    for (int ht = 0; ht < 4; ++ht)
#pragma unroll
        for (int rg = 0; rg < 4; ++rg) {
            const size_t m = (size_t)(b * TT + q0 + woff + lg * 4 + rg);
            out[m * 64 + ht * 16 + lr] = o[ht][rg] * inv[rg];
        }
}

// ---------------------------------------------------------------------------
extern "C" void kernel_launch(void* const* d_in, const int* in_sizes, int n_in,
                              void* d_out, int out_size, void* d_ws, size_t ws_size,
                              hipStream_t stream)
{
    const float* emb = (const float*)d_in[0];
    const float* Wk  = (const float*)d_in[1];
    const float* bk  = (const float*)d_in[2];
    const float* Wq  = (const float*)d_in[3];
    const float* bq  = (const float*)d_in[4];
    const float* Wv  = (const float*)d_in[5];
    const float* bv  = (const float*)d_in[6];
    float* out = (float*)d_out;

    // ws layout (bytes): Qb[2MB] Kb[2MB] Vt[2MB] Wt[384KB]
    char* base = (char*)d_ws;
    unsigned short* Qb = (unsigned short*)(base);
    unsigned short* Kb = (unsigned short*)(base + (2u << 20));
    unsigned short* Vt = (unsigned short*)(base + (4u << 20));
    unsigned short* Wt = (unsigned short*)(base + (6u << 20));

    prep_wt<<<192 * 1024 / 256, 256, 0, stream>>>(Wk, Wq, Wv, Wt);
    qkv_mfma<<<(NB * TT) / 64, 256, 0, stream>>>(emb, Wt, bk, bq, bv, Qb, Kb, Vt);
    attn_mfma<<<512, 128, 0, stream>>>(Qb, Kb, Vt, out);
}

// Round 3
// 108.232 us; speedup vs baseline: 11.3712x; 2.1121x over previous
//
#include <hip/hip_runtime.h>
#include <hip/hip_bf16.h>

// SelfAttentionHead: EMB=1024, KEY=HEAD=64, B=4, T=4096
#define EMB 1024
#define NB  4
#define TT  4096
#define DD  64

// fold 1/sqrt(64) and log2(e) into Q so softmax runs in exp2 domain
static constexpr float SCALE2 = 0.125f * 1.4426950408889634f;

typedef __bf16          bfrag    __attribute__((ext_vector_type(8)));
typedef float           f32x4    __attribute__((ext_vector_type(4)));
typedef unsigned short  ushort8t __attribute__((ext_vector_type(8)));
typedef unsigned short  ushort4t __attribute__((ext_vector_type(4)));

__device__ __forceinline__ unsigned short f2bf(float f) {
    __hip_bfloat16 h = __float2bfloat16(f);   // RNE
    return __builtin_bit_cast(unsigned short, h);
}

// ---------------------------------------------------------------------------
// Prep: Wt[n][k] bf16, n in [0,192) = concat(Wk, Wq*SCALE2, Wv) columns.
// ---------------------------------------------------------------------------
__global__ __launch_bounds__(256) void prep_wt(
    const float* __restrict__ Wk, const float* __restrict__ Wq,
    const float* __restrict__ Wv, unsigned short* __restrict__ Wt)
{
    const int o = blockIdx.x * 256 + threadIdx.x;   // 0 .. 192*1024-1
    const int n = o >> 10, k = o & 1023;
    float v;
    if (n < 64)       v = Wk[k * 64 + n];
    else if (n < 128) v = Wq[k * 64 + (n - 64)] * SCALE2;
    else              v = Wv[k * 64 + (n - 128)];
    Wt[o] = f2bf(v);
}

// ---------------------------------------------------------------------------
// QKV projection as bf16 MFMA GEMM (M-tile 64, 4 waves). Outputs Q/K bf16
// row-major (Q pre-scaled), V transposed [b][h][t].
// ---------------------------------------------------------------------------
#define PSTR 66   // 132B = 33 dwords (odd) -> ~2-way max on staging, <=4-way frag reads

__global__ __launch_bounds__(256) void qkv_mfma(
    const float* __restrict__ emb,
    const unsigned short* __restrict__ Wt,
    const float* __restrict__ bk, const float* __restrict__ bq,
    const float* __restrict__ bv,
    unsigned short* __restrict__ Qb, unsigned short* __restrict__ Kb,
    unsigned short* __restrict__ Vt)
{
    __shared__ unsigned short elds[64 * PSTR];
    __shared__ unsigned short wlds[192 * PSTR];

    const int tid = threadIdx.x;
    const int w = tid >> 6, l = tid & 63;
    const int lr = l & 15, lg = l >> 4;
    const int m0 = blockIdx.x * 64;

    f32x4 acc[12];
#pragma unroll
    for (int i = 0; i < 12; ++i) acc[i] = (f32x4){0.f, 0.f, 0.f, 0.f};

    const int er = tid >> 2, ec = (tid & 3) * 16;

    for (int k0 = 0; k0 < EMB; k0 += 64) {
        {
            const float* src = emb + (size_t)(m0 + er) * EMB + k0 + ec;
            float4 f0 = *(const float4*)(src + 0);
            float4 f1 = *(const float4*)(src + 4);
            float4 f2 = *(const float4*)(src + 8);
            float4 f3 = *(const float4*)(src + 12);
            ushort8t lo, hi;
            lo[0]=f2bf(f0.x); lo[1]=f2bf(f0.y); lo[2]=f2bf(f0.z); lo[3]=f2bf(f0.w);
            lo[4]=f2bf(f1.x); lo[5]=f2bf(f1.y); lo[6]=f2bf(f1.z); lo[7]=f2bf(f1.w);
            hi[0]=f2bf(f2.x); hi[1]=f2bf(f2.y); hi[2]=f2bf(f2.z); hi[3]=f2bf(f2.w);
            hi[4]=f2bf(f3.x); hi[5]=f2bf(f3.y); hi[6]=f2bf(f3.z); hi[7]=f2bf(f3.w);
            *(ushort8t*)&elds[er * PSTR + ec]     = lo;
            *(ushort8t*)&elds[er * PSTR + ec + 8] = hi;
        }
#pragma unroll
        for (int i = 0; i < 6; ++i) {
            const int idx = tid + i * 256;
            const int row = idx >> 3, c = (idx & 7) * 8;
            *(ushort8t*)&wlds[row * PSTR + c] =
                *(const ushort8t*)&Wt[(size_t)row * 1024 + k0 + c];
        }
        __syncthreads();
#pragma unroll
        for (int c = 0; c < 2; ++c) {
            bfrag a = *(const bfrag*)&elds[(w * 16 + lr) * PSTR + c * 32 + lg * 8];
#pragma unroll
            for (int nt = 0; nt < 12; ++nt) {
                bfrag bb = *(const bfrag*)&wlds[(nt * 16 + lr) * PSTR + c * 32 + lg * 8];
                acc[nt] = __builtin_amdgcn_mfma_f32_16x16x32_bf16(a, bb, acc[nt], 0, 0, 0);
            }
        }
        __syncthreads();
    }

    const int rbase = m0 + w * 16 + lg * 4;
#pragma unroll
    for (int nt = 0; nt < 12; ++nt) {
        const int n = nt * 16 + lr;
        float bias;
        if (n < 64)       bias = bk[n];
        else if (n < 128) bias = bq[n - 64] * SCALE2;
        else              bias = bv[n - 128];
        if (nt < 8) {
            unsigned short* dst = (nt < 4) ? Kb : Qb;
            const int d = (nt < 4) ? n : (n - 64);
#pragma unroll
            for (int rg = 0; rg < 4; ++rg)
                dst[(size_t)(rbase + rg) * 64 + d] = f2bf(acc[nt][rg] + bias);
        } else {
            const int h = n - 128;
            const int b = rbase >> 12, t = rbase & (TT - 1);
            ushort4t pk;
#pragma unroll
            for (int rg = 0; rg < 4; ++rg) pk[rg] = f2bf(acc[nt][rg] + bias);
            *(ushort4t*)&Vt[((size_t)b * 64 + h) * TT + t] = pk;
        }
    }
}

// ---------------------------------------------------------------------------
// Flash attention partials, split-K. grid = 512*nch blocks, block=128 (2
// waves). Block = (b, q-tile of 32 rows, key-chunk of `chunk` 64-key tiles).
// Writes unnormalized (o, m, l) partials; attn_merge combines.
// Heavy-first ti order; T14 async-stage (prefetch next tile during compute).
// ---------------------------------------------------------------------------
#define ASTR 66

__global__ __launch_bounds__(128) void attn_part(
    const unsigned short* __restrict__ Qb,
    const unsigned short* __restrict__ Kb,
    const unsigned short* __restrict__ Vt,
    float* __restrict__ po, float* __restrict__ pml,
    int chunk, int nch)
{
    __shared__ unsigned short klds[64 * ASTR];
    __shared__ unsigned short vlds[64 * ASTR];
    __shared__ unsigned short plds[32 * ASTR];

    const int idx = blockIdx.x;
    const int c   = idx >> 9;              // chunk layer
    const int b   = idx & 3;
    const int ti  = 127 - ((idx >> 2) & 127);   // heavy-first
    const int nkt = (ti >> 1) + 1;
    const int kt0 = c * chunk;
    if (kt0 >= nkt) return;
    const int kt1 = min(nkt, kt0 + chunk);

    const int tid = threadIdx.x;
    const int w = tid >> 6, l = tid & 63;
    const int lr = l & 15, lg = l >> 4;
    const int q0 = ti * 32;
    const int woff = w * 16;

    bfrag qa0, qa1;
    {
        const size_t qrow = (size_t)(b * TT + q0 + woff + lr) * 64;
        qa0 = *(const bfrag*)&Qb[qrow + 0  + lg * 8];
        qa1 = *(const bfrag*)&Qb[qrow + 32 + lg * 8];
    }

    f32x4 o[4];
#pragma unroll
    for (int i = 0; i < 4; ++i) o[i] = (f32x4){0.f, 0.f, 0.f, 0.f};
    float mrow[4] = {-1e30f, -1e30f, -1e30f, -1e30f};
    float lrow[4] = {0.f, 0.f, 0.f, 0.f};

    const int srow = tid >> 3, scol = (tid & 7) * 8;

    ushort8t kreg[4], vreg[4];
    {
        const int k0 = kt0 * 64;
#pragma unroll
        for (int i = 0; i < 4; ++i) {
            const int row = srow + i * 16;
            kreg[i] = *(const ushort8t*)&Kb[(size_t)(b * TT + k0 + row) * 64 + scol];
            vreg[i] = *(const ushort8t*)&Vt[((size_t)b * 64 + row) * TT + k0 + scol];
        }
    }

    for (int kt = kt0; kt < kt1; ++kt) {
        // write staged regs -> LDS
#pragma unroll
        for (int i = 0; i < 4; ++i) {
            const int row = srow + i * 16;
            *(ushort8t*)&klds[row * ASTR + scol] = kreg[i];
            *(ushort8t*)&vlds[row * ASTR + scol] = vreg[i];
        }
        __syncthreads();

        // T14: issue next tile's global loads now; they complete under compute
        if (kt + 1 < kt1) {
            const int k0n = (kt + 1) * 64;
#pragma unroll
            for (int i = 0; i < 4; ++i) {
                const int row = srow + i * 16;
                kreg[i] = *(const ushort8t*)&Kb[(size_t)(b * TT + k0n + row) * 64 + scol];
                vreg[i] = *(const ushort8t*)&Vt[((size_t)b * 64 + row) * TT + k0n + scol];
            }
        }

        // S = Q K^T
        f32x4 s[4];
#pragma unroll
        for (int i = 0; i < 4; ++i) s[i] = (f32x4){0.f, 0.f, 0.f, 0.f};
#pragma unroll
        for (int nt = 0; nt < 4; ++nt) {
            bfrag kb0 = *(const bfrag*)&klds[(nt * 16 + lr) * ASTR + 0  + lg * 8];
            bfrag kb1 = *(const bfrag*)&klds[(nt * 16 + lr) * ASTR + 32 + lg * 8];
            s[nt] = __builtin_amdgcn_mfma_f32_16x16x32_bf16(qa0, kb0, s[nt], 0, 0, 0);
            s[nt] = __builtin_amdgcn_mfma_f32_16x16x32_bf16(qa1, kb1, s[nt], 0, 0, 0);
        }

        // causal mask on the diagonal tile
        if (kt == nkt - 1) {
            const int k0 = kt * 64;
#pragma unroll
            for (int nt = 0; nt < 4; ++nt) {
                const int key = k0 + nt * 16 + lr;
#pragma unroll
                for (int rg = 0; rg < 4; ++rg) {
                    const int qr = q0 + woff + lg * 4 + rg;
                    if (key > qr) s[nt][rg] = -1e30f;
                }
            }
        }

        // online softmax
        float tm[4];
#pragma unroll
        for (int rg = 0; rg < 4; ++rg)
            tm[rg] = fmaxf(fmaxf(s[0][rg], s[1][rg]), fmaxf(s[2][rg], s[3][rg]));
#pragma unroll
        for (int mk = 1; mk <= 8; mk <<= 1)
#pragma unroll
            for (int rg = 0; rg < 4; ++rg)
                tm[rg] = fmaxf(tm[rg], __shfl_xor(tm[rg], mk));

        float corr[4], rs[4];
#pragma unroll
        for (int rg = 0; rg < 4; ++rg) {
            const float nm = fmaxf(mrow[rg], tm[rg]);
            corr[rg] = exp2f(mrow[rg] - nm);
            mrow[rg] = nm;
            rs[rg] = 0.f;
        }
        float p[4][4];
#pragma unroll
        for (int nt = 0; nt < 4; ++nt)
#pragma unroll
            for (int rg = 0; rg < 4; ++rg) {
                const float pp = exp2f(s[nt][rg] - mrow[rg]);
                p[nt][rg] = pp;
                rs[rg] += pp;
            }
#pragma unroll
        for (int mk = 1; mk <= 8; mk <<= 1)
#pragma unroll
            for (int rg = 0; rg < 4; ++rg)
                rs[rg] += __shfl_xor(rs[rg], mk);
#pragma unroll
        for (int rg = 0; rg < 4; ++rg)
            lrow[rg] = lrow[rg] * corr[rg] + rs[rg];
#pragma unroll
        for (int nt = 0; nt < 4; ++nt)
#pragma unroll
            for (int rg = 0; rg < 4; ++rg)
                o[nt][rg] *= corr[rg];

        // P -> LDS bf16 (own wave's rows; DS in-order per wave, no barrier)
#pragma unroll
        for (int nt = 0; nt < 4; ++nt)
#pragma unroll
            for (int rg = 0; rg < 4; ++rg)
                plds[(woff + lg * 4 + rg) * ASTR + nt * 16 + lr] = f2bf(p[nt][rg]);

        // PV
#pragma unroll
        for (int cc = 0; cc < 2; ++cc) {
            bfrag pa = *(const bfrag*)&plds[(woff + lr) * ASTR + cc * 32 + lg * 8];
#pragma unroll
            for (int ht = 0; ht < 4; ++ht) {
                bfrag vb = *(const bfrag*)&vlds[(ht * 16 + lr) * ASTR + cc * 32 + lg * 8];
                o[ht] = __builtin_amdgcn_mfma_f32_16x16x32_bf16(pa, vb, o[ht], 0, 0, 0);
            }
        }
        __syncthreads();
    }

    // store partials (unnormalized o, plus m, l per row)
    const int slot = ((b << 7) + ti) * nch + c;
    const size_t pob = (size_t)slot * 2048;
#pragma unroll
    for (int ht = 0; ht < 4; ++ht)
#pragma unroll
        for (int rg = 0; rg < 4; ++rg) {
            const int row = woff + lg * 4 + rg;
            po[pob + row * 64 + ht * 16 + lr] = o[ht][rg];
        }
    if (lr == 0) {
#pragma unroll
        for (int rg = 0; rg < 4; ++rg) {
            const int row = woff + lg * 4 + rg;
            pml[slot * 64 + row]      = mrow[rg];
            pml[slot * 64 + 32 + row] = lrow[rg];
        }
    }
}

// ---------------------------------------------------------------------------
// Merge split-K partials. grid=512 (one block per (b, q-tile)), 256 threads.
// Thread handles one row x 8 cols.
// ---------------------------------------------------------------------------
__global__ __launch_bounds__(256) void attn_merge(
    const float* __restrict__ po, const float* __restrict__ pml,
    float* __restrict__ out, int chunk, int nch)
{
    const int idx = blockIdx.x;      // 0..511
    const int b = idx & 3;
    const int ti = idx >> 2;
    const int nkt = (ti >> 1) + 1;
    const int nc = min(nch, (nkt + chunk - 1) / chunk);
    const int r  = threadIdx.x >> 3;
    const int c0 = (threadIdx.x & 7) * 8;
    const int base_slot = ((b << 7) + ti) * nch;

    float M = -1e30f;
    for (int c = 0; c < nc; ++c)
        M = fmaxf(M, pml[(base_slot + c) * 64 + r]);

    float den = 0.f;
    float acc[8];
#pragma unroll
    for (int i = 0; i < 8; ++i) acc[i] = 0.f;

    for (int c = 0; c < nc; ++c) {
        const float wgt = exp2f(pml[(base_slot + c) * 64 + r] - M);
        den += wgt * pml[(base_slot + c) * 64 + 32 + r];
        const float* src = po + (size_t)(base_slot + c) * 2048 + r * 64 + c0;
        const float4 v0 = *(const float4*)(src);
        const float4 v1 = *(const float4*)(src + 4);
        acc[0] += wgt * v0.x; acc[1] += wgt * v0.y;
        acc[2] += wgt * v0.z; acc[3] += wgt * v0.w;
        acc[4] += wgt * v1.x; acc[5] += wgt * v1.y;
        acc[6] += wgt * v1.z; acc[7] += wgt * v1.w;
    }
    const float inv = 1.0f / den;
    float* dst = out + ((size_t)b * TT + ti * 32 + r) * 64 + c0;
    float4 o0 = {acc[0] * inv, acc[1] * inv, acc[2] * inv, acc[3] * inv};
    float4 o1 = {acc[4] * inv, acc[5] * inv, acc[6] * inv, acc[7] * inv};
    *(float4*)(dst)     = o0;
    *(float4*)(dst + 4) = o1;
}

// ---------------------------------------------------------------------------
extern "C" void kernel_launch(void* const* d_in, const int* in_sizes, int n_in,
                              void* d_out, int out_size, void* d_ws, size_t ws_size,
                              hipStream_t stream)
{
    const float* emb = (const float*)d_in[0];
    const float* Wk  = (const float*)d_in[1];
    const float* bk  = (const float*)d_in[2];
    const float* Wq  = (const float*)d_in[3];
    const float* bq  = (const float*)d_in[4];
    const float* Wv  = (const float*)d_in[5];
    const float* bv  = (const float*)d_in[6];
    float* out = (float*)d_out;

    // ws layout: Qb[2MB] Kb[2MB] Vt[2MB] Wt[384KB] | po | pml
    char* base = (char*)d_ws;
    unsigned short* Qb = (unsigned short*)(base);
    unsigned short* Kb = (unsigned short*)(base + (2u << 20));
    unsigned short* Vt = (unsigned short*)(base + (4u << 20));
    unsigned short* Wt = (unsigned short*)(base + (6u << 20));
    const size_t pbase = (size_t)7 << 20;

    // pick split-K factor to fit workspace: nch=4 needs ~23.5MB total
    int nch = 4, chunk = 16;
    {
        const size_t need = pbase + (size_t)512 * nch * (2048 + 64) * sizeof(float);
        if (ws_size < need) { nch = 1; chunk = 64; }   // fallback: round-2 behavior
    }
    float* po  = (float*)(base + pbase);
    float* pml = po + (size_t)512 * nch * 2048;

    prep_wt<<<192 * 1024 / 256, 256, 0, stream>>>(Wk, Wq, Wv, Wt);
    qkv_mfma<<<(NB * TT) / 64, 256, 0, stream>>>(emb, Wt, bk, bq, bv, Qb, Kb, Vt);
    attn_part<<<512 * nch, 128, 0, stream>>>(Qb, Kb, Vt, po, pml, chunk, nch);
    attn_merge<<<512, 256, 0, stream>>>(po, pml, out, chunk, nch);
}

// Round 4
// 85.848 us; speedup vs baseline: 14.3362x; 1.2607x over previous
//
#include <hip/hip_runtime.h>
#include <hip/hip_bf16.h>

// SelfAttentionHead: EMB=1024, KEY=HEAD=64, B=4, T=4096
#define EMB 1024
#define NB  4
#define TT  4096
#define DD  64

// fold 1/sqrt(64) and log2(e) into Q so softmax runs in exp2 domain
static constexpr float SCALE2 = 0.125f * 1.4426950408889634f;

typedef __bf16          bfrag    __attribute__((ext_vector_type(8)));
typedef float           f32x4    __attribute__((ext_vector_type(4)));
typedef unsigned short  ushort8t __attribute__((ext_vector_type(8)));
typedef unsigned short  ushort4t __attribute__((ext_vector_type(4)));
typedef unsigned int    uint32;

__device__ __forceinline__ unsigned short f2bf(float f) {
    __hip_bfloat16 h = __float2bfloat16(f);   // RNE
    return __builtin_bit_cast(unsigned short, h);
}
__device__ __forceinline__ float bf2f(unsigned short u) {
    uint32 v = ((uint32)u) << 16;
    return __builtin_bit_cast(float, v);
}
__device__ __forceinline__ uint32 pk2(float a, float b) {
    return (uint32)f2bf(a) | ((uint32)f2bf(b) << 16);
}

// ---------------------------------------------------------------------------
// Prep: Wt[n][k] bf16, n in [0,192) = concat(Wk, Wq*SCALE2, Wv) columns.
// ---------------------------------------------------------------------------
__global__ __launch_bounds__(256) void prep_wt(
    const float* __restrict__ Wk, const float* __restrict__ Wq,
    const float* __restrict__ Wv, unsigned short* __restrict__ Wt)
{
    const int o = blockIdx.x * 256 + threadIdx.x;   // 0 .. 192*1024-1
    const int n = o >> 10, k = o & 1023;
    float v;
    if (n < 64)       v = Wk[k * 64 + n];
    else if (n < 128) v = Wq[k * 64 + (n - 64)] * SCALE2;
    else              v = Wv[k * 64 + (n - 128)];
    Wt[o] = f2bf(v);
}

// ---------------------------------------------------------------------------
// QKV projection, bf16 MFMA GEMM (M-tile 64, 4 waves) with T14 reg-prefetch:
// next k-step's emb/W tiles load into regs while MFMAs run on the current
// LDS tiles. Outputs Q/K bf16 row-major (Q pre-scaled), V^T [b][h][t].
// ---------------------------------------------------------------------------
#define PSTR 66

__global__ __launch_bounds__(256) void qkv_mfma(
    const float* __restrict__ emb,
    const unsigned short* __restrict__ Wt,
    const float* __restrict__ bk, const float* __restrict__ bq,
    const float* __restrict__ bv,
    unsigned short* __restrict__ Qb, unsigned short* __restrict__ Kb,
    unsigned short* __restrict__ Vt)
{
    __shared__ unsigned short elds[64 * PSTR];
    __shared__ unsigned short wlds[192 * PSTR];

    const int tid = threadIdx.x;
    const int w = tid >> 6, l = tid & 63;
    const int lr = l & 15, lg = l >> 4;
    const int m0 = blockIdx.x * 64;

    f32x4 acc[12];
#pragma unroll
    for (int i = 0; i < 12; ++i) acc[i] = (f32x4){0.f, 0.f, 0.f, 0.f};

    const int er = tid >> 2, ec = (tid & 3) * 16;

    float4 f0, f1, f2, f3;
    ushort8t wr[6];
    {   // prologue: load k0 = 0 tiles into regs
        const float* src = emb + (size_t)(m0 + er) * EMB + ec;
        f0 = *(const float4*)(src + 0);
        f1 = *(const float4*)(src + 4);
        f2 = *(const float4*)(src + 8);
        f3 = *(const float4*)(src + 12);
#pragma unroll
        for (int i = 0; i < 6; ++i) {
            const int idx = tid + i * 256;
            const int row = idx >> 3, c = (idx & 7) * 8;
            wr[i] = *(const ushort8t*)&Wt[(size_t)row * 1024 + c];
        }
    }

    for (int it = 0; it < 16; ++it) {
        __syncthreads();   // previous iteration's MFMA reads are done
        {   // write staged regs -> LDS (f32 -> bf16 for emb)
            ushort8t lo, hi;
            lo[0]=f2bf(f0.x); lo[1]=f2bf(f0.y); lo[2]=f2bf(f0.z); lo[3]=f2bf(f0.w);
            lo[4]=f2bf(f1.x); lo[5]=f2bf(f1.y); lo[6]=f2bf(f1.z); lo[7]=f2bf(f1.w);
            hi[0]=f2bf(f2.x); hi[1]=f2bf(f2.y); hi[2]=f2bf(f2.z); hi[3]=f2bf(f2.w);
            hi[4]=f2bf(f3.x); hi[5]=f2bf(f3.y); hi[6]=f2bf(f3.z); hi[7]=f2bf(f3.w);
            *(ushort8t*)&elds[er * PSTR + ec]     = lo;
            *(ushort8t*)&elds[er * PSTR + ec + 8] = hi;
#pragma unroll
            for (int i = 0; i < 6; ++i) {
                const int idx = tid + i * 256;
                const int row = idx >> 3, c = (idx & 7) * 8;
                *(ushort8t*)&wlds[row * PSTR + c] = wr[i];
            }
        }
        // prefetch next k-step into regs (completes under the MFMA phase)
        if (it < 15) {
            const int kn = (it + 1) * 64;
            const float* src = emb + (size_t)(m0 + er) * EMB + kn + ec;
            f0 = *(const float4*)(src + 0);
            f1 = *(const float4*)(src + 4);
            f2 = *(const float4*)(src + 8);
            f3 = *(const float4*)(src + 12);
#pragma unroll
            for (int i = 0; i < 6; ++i) {
                const int idx = tid + i * 256;
                const int row = idx >> 3, c = (idx & 7) * 8;
                wr[i] = *(const ushort8t*)&Wt[(size_t)row * 1024 + kn + c];
            }
        }
        __syncthreads();
#pragma unroll
        for (int c = 0; c < 2; ++c) {
            bfrag a = *(const bfrag*)&elds[(w * 16 + lr) * PSTR + c * 32 + lg * 8];
#pragma unroll
            for (int nt = 0; nt < 12; ++nt) {
                bfrag bb = *(const bfrag*)&wlds[(nt * 16 + lr) * PSTR + c * 32 + lg * 8];
                acc[nt] = __builtin_amdgcn_mfma_f32_16x16x32_bf16(a, bb, acc[nt], 0, 0, 0);
            }
        }
    }

    const int rbase = m0 + w * 16 + lg * 4;
#pragma unroll
    for (int nt = 0; nt < 12; ++nt) {
        const int n = nt * 16 + lr;
        float bias;
        if (n < 64)       bias = bk[n];
        else if (n < 128) bias = bq[n - 64] * SCALE2;
        else              bias = bv[n - 128];
        if (nt < 8) {
            unsigned short* dst = (nt < 4) ? Kb : Qb;
            const int d = (nt < 4) ? n : (n - 64);
#pragma unroll
            for (int rg = 0; rg < 4; ++rg)
                dst[(size_t)(rbase + rg) * 64 + d] = f2bf(acc[nt][rg] + bias);
        } else {
            const int h = n - 128;
            const int b = rbase >> 12, t = rbase & (TT - 1);
            ushort4t pk;
#pragma unroll
            for (int rg = 0; rg < 4; ++rg) pk[rg] = f2bf(acc[nt][rg] + bias);
            *(ushort4t*)&Vt[((size_t)b * 64 + h) * TT + t] = pk;
        }
    }
}

// ---------------------------------------------------------------------------
// Flash attention partials: 1-wave blocks (64 thr), NO barriers, split-K.
// Block = (b, 32-row q-tile ti32, chunk c of `chunk` 64-key tiles).
// Swapped QK^T: S^T = mfma(K, Q) so lane (lr,g) owns q-row lr's scores at
// keys nt*16+4g+rg; row softmax = 2 shfl_xor. K/V fragments load DIRECTLY
// from global (L2-hot). P round-trips a wave-private 4.2KB LDS buffer
// (in-order DS per wave -> no barrier). Partials: o bf16 (coded C-layout,
// coalesced) + (m,l) f32.
// ---------------------------------------------------------------------------
#define PST 66

__global__ __launch_bounds__(64) void attn_part(
    const unsigned short* __restrict__ Qb,
    const unsigned short* __restrict__ Kb,
    const unsigned short* __restrict__ Vt,
    unsigned short* __restrict__ po, float* __restrict__ pml,
    int chunk, int nch)
{
    __shared__ unsigned short plds[32 * PST];

    const int idx  = blockIdx.x;
    const int c    = idx >> 9;                    // chunk layer
    const int b    = idx & 3;
    const int ti32 = 127 - ((idx >> 2) & 127);    // heavy-first
    const int nkt  = (ti32 >> 1) + 1;
    const int kt0  = c * chunk;
    if (kt0 >= nkt) return;
    const int kt1 = min(nkt, kt0 + chunk);

    const int l  = threadIdx.x;
    const int lr = l & 15, g = l >> 4;
    const int q0 = ti32 * 32;
    const size_t bTT = (size_t)b * TT;

    // Q fragments (B-operand): lane holds Q[q0+s*16+lr][k=g*8..+7]
    bfrag qa[2][2];
#pragma unroll
    for (int s = 0; s < 2; ++s) {
        const size_t qr = (bTT + q0 + s * 16 + lr) * 64 + g * 8;
        qa[s][0] = *(const bfrag*)&Qb[qr];
        qa[s][1] = *(const bfrag*)&Qb[qr + 32];
    }

    f32x4 o[2][4];
#pragma unroll
    for (int s = 0; s < 2; ++s)
#pragma unroll
        for (int ht = 0; ht < 4; ++ht) o[s][ht] = (f32x4){0.f, 0.f, 0.f, 0.f};
    float mrow[2] = {-1e30f, -1e30f};
    float lrow[2] = {0.f, 0.f};

    for (int kt = kt0; kt < kt1; ++kt) {
        const int k0 = kt * 64;

        // K fragments (A-operand): K[key=k0+nt*16+lr][k=g*8..]
        bfrag kf[4][2];
#pragma unroll
        for (int nt = 0; nt < 4; ++nt) {
            const size_t kr = (bTT + k0 + nt * 16 + lr) * 64 + g * 8;
            kf[nt][0] = *(const bfrag*)&Kb[kr];
            kf[nt][1] = *(const bfrag*)&Kb[kr + 32];
        }
        // V fragments (B-operand for PV): V^T[h=ht*16+lr][k0+cc*32+g*8..]
        bfrag vf[4][2];
#pragma unroll
        for (int ht = 0; ht < 4; ++ht) {
            const size_t vr = ((size_t)b * 64 + ht * 16 + lr) * TT + k0 + g * 8;
            vf[ht][0] = *(const bfrag*)&Vt[vr];
            vf[ht][1] = *(const bfrag*)&Vt[vr + 32];
        }
        const bool diag = (kt == nkt - 1);

#pragma unroll
        for (int s = 0; s < 2; ++s) {
            // S^T tiles: lane (lr,g) reg rg = S[q0+s*16+lr][k0+nt*16+4g+rg]
            f32x4 sv[4];
#pragma unroll
            for (int nt = 0; nt < 4; ++nt) {
                sv[nt] = (f32x4){0.f, 0.f, 0.f, 0.f};
                sv[nt] = __builtin_amdgcn_mfma_f32_16x16x32_bf16(kf[nt][0], qa[s][0], sv[nt], 0, 0, 0);
                sv[nt] = __builtin_amdgcn_mfma_f32_16x16x32_bf16(kf[nt][1], qa[s][1], sv[nt], 0, 0, 0);
            }
            const int qrow = q0 + s * 16 + lr;
            if (diag) {
#pragma unroll
                for (int nt = 0; nt < 4; ++nt)
#pragma unroll
                    for (int rg = 0; rg < 4; ++rg) {
                        const int key = k0 + nt * 16 + 4 * g + rg;
                        if (key > qrow) sv[nt][rg] = -1e30f;
                    }
            }
            // row max (row data lives at lanes lr, lr+16, lr+32, lr+48)
            float pm = sv[0][0];
#pragma unroll
            for (int nt = 0; nt < 4; ++nt)
#pragma unroll
                for (int rg = 0; rg < 4; ++rg) pm = fmaxf(pm, sv[nt][rg]);
            pm = fmaxf(pm, __shfl_xor(pm, 16));
            pm = fmaxf(pm, __shfl_xor(pm, 32));

            // defer-max (T13): only rescale when max grows by > 8
            if (!__all(pm - mrow[s] <= 8.0f)) {
                const float nm = fmaxf(mrow[s], pm);
                const float cr = exp2f(mrow[s] - nm);
                mrow[s] = nm;
                lrow[s] *= cr;
#pragma unroll
                for (int ht = 0; ht < 4; ++ht) o[s][ht] *= cr;
            }

            // P = exp2(S - m), packed to bf16 pairs, local+cross-lane sum
            float ls = 0.f;
            uint32 pw[8];
#pragma unroll
            for (int nt = 0; nt < 4; ++nt)
#pragma unroll
                for (int h = 0; h < 2; ++h) {
                    const float pa_ = exp2f(sv[nt][2 * h]     - mrow[s]);
                    const float pb_ = exp2f(sv[nt][2 * h + 1] - mrow[s]);
                    ls += pa_ + pb_;
                    pw[nt * 2 + h] = pk2(pa_, pb_);
                }
            ls += __shfl_xor(ls, 16);
            ls += __shfl_xor(ls, 32);
            lrow[s] += ls;

            // P -> wave-private LDS (row = s*16+lr, key cols 4g..)
            const int prow = (s * 16 + lr) * PST;
#pragma unroll
            for (int nt = 0; nt < 4; ++nt)
#pragma unroll
                for (int h = 0; h < 2; ++h)
                    *(uint32*)&plds[prow + nt * 16 + 4 * g + 2 * h] = pw[nt * 2 + h];

            // PV: O[s] += P V   (A-frag read back from plds)
#pragma unroll
            for (int cc = 0; cc < 2; ++cc) {
                bfrag pa = *(const bfrag*)&plds[prow + cc * 32 + g * 8];
#pragma unroll
                for (int ht = 0; ht < 4; ++ht)
                    o[s][ht] = __builtin_amdgcn_mfma_f32_16x16x32_bf16(pa, vf[ht][cc], o[s][ht], 0, 0, 0);
            }
        }
    }

    // store partials: po coded C-layout bf16 (coalesced), pml (m,l) f32
    const int slot = (((b << 7) + ti32) * nch) + c;
    const size_t pob = (size_t)slot * 2048;
#pragma unroll
    for (int s = 0; s < 2; ++s)
#pragma unroll
        for (int ht = 0; ht < 4; ++ht)
#pragma unroll
            for (int rg = 0; rg < 4; ++rg)
                po[pob + (size_t)(((s * 4 + ht) * 4 + rg) * 64 + l)] = f2bf(o[s][ht][rg]);
    if (g == 0) {
#pragma unroll
        for (int s = 0; s < 2; ++s) {
            pml[slot * 64 + s * 16 + lr]      = mrow[s];
            pml[slot * 64 + 32 + s * 16 + lr] = lrow[s];
        }
    }
}

// ---------------------------------------------------------------------------
// Merge split-K partials. grid = 512 (one per (b, ti32)), 256 threads; each
// thread owns 8 coded elements (same row, 8 consecutive cols).
// ---------------------------------------------------------------------------
__global__ __launch_bounds__(256) void attn_merge(
    const unsigned short* __restrict__ po, const float* __restrict__ pml,
    float* __restrict__ out, int chunk, int nch)
{
    const int idx  = blockIdx.x;      // 0..511
    const int b    = idx & 3;
    const int ti32 = idx >> 2;
    const int nkt  = (ti32 >> 1) + 1;
    const int nc   = (nkt + chunk - 1) / chunk;

    const int e0   = threadIdx.x * 8;
    const int lane = e0 & 63;
    const int rg   = (e0 >> 6) & 3;
    const int ht   = (e0 >> 8) & 3;
    const int s    = e0 >> 10;
    const int row  = s * 16 + ((lane >> 4) << 2) + rg;
    const int col0 = ht * 16 + (lane & 15);
    const int slot0 = ((b << 7) + ti32) * nch;

    float M = -1e30f;
    for (int c = 0; c < nc; ++c)
        M = fmaxf(M, pml[(slot0 + c) * 64 + row]);

    float den = 0.f;
    float acc[8];
#pragma unroll
    for (int i = 0; i < 8; ++i) acc[i] = 0.f;

    for (int c = 0; c < nc; ++c) {
        const float wgt = exp2f(pml[(slot0 + c) * 64 + row] - M);
        den += wgt * pml[(slot0 + c) * 64 + 32 + row];
        const ushort8t v = *(const ushort8t*)&po[(size_t)(slot0 + c) * 2048 + e0];
#pragma unroll
        for (int j = 0; j < 8; ++j) acc[j] += wgt * bf2f(v[j]);
    }
    const float inv = 1.0f / den;
    float* dst = out + ((size_t)b * TT + ti32 * 32 + row) * 64 + col0;
    float4 o0 = {acc[0] * inv, acc[1] * inv, acc[2] * inv, acc[3] * inv};
    float4 o1 = {acc[4] * inv, acc[5] * inv, acc[6] * inv, acc[7] * inv};
    *(float4*)(dst)     = o0;
    *(float4*)(dst + 4) = o1;
}

// ---------------------------------------------------------------------------
extern "C" void kernel_launch(void* const* d_in, const int* in_sizes, int n_in,
                              void* d_out, int out_size, void* d_ws, size_t ws_size,
                              hipStream_t stream)
{
    const float* emb = (const float*)d_in[0];
    const float* Wk  = (const float*)d_in[1];
    const float* bk  = (const float*)d_in[2];
    const float* Wq  = (const float*)d_in[3];
    const float* bq  = (const float*)d_in[4];
    const float* Wv  = (const float*)d_in[5];
    const float* bv  = (const float*)d_in[6];
    float* out = (float*)d_out;

    // ws: Qb[2MB] Kb[2MB] Vt[2MB] Wt[384KB] | po (bf16) | pml (f32)
    char* base = (char*)d_ws;
    unsigned short* Qb = (unsigned short*)(base);
    unsigned short* Kb = (unsigned short*)(base + (2u << 20));
    unsigned short* Vt = (unsigned short*)(base + (4u << 20));
    unsigned short* Wt = (unsigned short*)(base + (6u << 20));
    const size_t pbase = ((size_t)6 << 20) + (512u << 10);   // 6.5 MB

    // split-K ladder (deterministic in ws_size): prefer nch=8 (fits the
    // round-3-proven >=24MB workspace)
    int nch = 8;
    for (;;) {
        const size_t need = pbase +
            (size_t)512 * nch * (2048 * sizeof(unsigned short) + 64 * sizeof(float));
        if (need <= ws_size || nch == 1) break;
        nch >>= 1;
    }
    const int chunk = 64 / nch;
    unsigned short* po = (unsigned short*)(base + pbase);
    float* pml = (float*)(po + (size_t)512 * nch * 2048);

    prep_wt<<<192 * 1024 / 256, 256, 0, stream>>>(Wk, Wq, Wv, Wt);
    qkv_mfma<<<(NB * TT) / 64, 256, 0, stream>>>(emb, Wt, bk, bq, bv, Qb, Kb, Vt);
    attn_part<<<512 * nch, 64, 0, stream>>>(Qb, Kb, Vt, po, pml, chunk, nch);
    attn_merge<<<512, 256, 0, stream>>>(po, pml, out, chunk, nch);
}